// Round 1
// baseline (981.916 us; speedup 1.0000x reference)
//
#include <hip/hip_runtime.h>

#define BN_EPS 1e-5f

// ---------------- CSR build ----------------

__global__ void hist_kernel(const int* __restrict__ ei, int* __restrict__ deg, int E, int n) {
  int e = blockIdx.x * blockDim.x + threadIdx.x;
  if (e >= E + n) return;
  int d = (e < E) ? ei[E + e] : (e - E);
  atomicAdd(&deg[d], 1);
}

// Single-block exclusive scan (chunked, shuffle-based). Writes indptr[0..n] and cursor[i]=indptr[i].
__global__ void __launch_bounds__(1024) scan_kernel(const int* __restrict__ deg,
                                                    int* __restrict__ indptr,
                                                    int* __restrict__ cursor, int n) {
  __shared__ int wsum[16];
  __shared__ int carry;
  int tid = threadIdx.x;
  int lane = tid & 63, wid = tid >> 6;
  if (tid == 0) { carry = 0; indptr[0] = 0; }
  __syncthreads();
  for (int base = 0; base < n; base += 1024) {
    int i = base + tid;
    int v = (i < n) ? deg[i] : 0;
    int incl = v;
#pragma unroll
    for (int off = 1; off < 64; off <<= 1) {
      int t = __shfl_up(incl, off, 64);
      if (lane >= off) incl += t;
    }
    if (lane == 63) wsum[wid] = incl;
    __syncthreads();
    if (wid == 0 && lane < 16) {
      int s = wsum[lane];
#pragma unroll
      for (int off = 1; off < 16; off <<= 1) {
        int t = __shfl_up(s, off, 16);
        if (lane >= off) s += t;
      }
      wsum[lane] = s;
    }
    __syncthreads();
    int woff = (wid > 0) ? wsum[wid - 1] : 0;
    incl += woff;
    int cbase = carry;
    if (i < n) {
      indptr[i + 1] = cbase + incl;
      cursor[i] = cbase + incl - v;
    }
    __syncthreads();
    if (tid == 0) carry = cbase + wsum[15];
    __syncthreads();
  }
}

__global__ void scatter_kernel(const int* __restrict__ ei, int* __restrict__ cursor,
                               int* __restrict__ csrc, int E, int n) {
  int e = blockIdx.x * blockDim.x + threadIdx.x;
  if (e >= E + n) return;
  int s, d;
  if (e < E) { s = ei[e]; d = ei[E + e]; } else { s = e - E; d = s; }
  int pos = atomicAdd(&cursor[d], 1);
  csrc[pos] = s;
}

// ---------------- node transform: xl = x@Wl+bl, xr = x@Wr+br ----------------

template <int CIN, int HC>
__global__ void transform_kernel(const float* __restrict__ x, const float* __restrict__ Wl,
                                 const float* __restrict__ Wr, const float* __restrict__ bl,
                                 const float* __restrict__ br, float* __restrict__ xl,
                                 float* __restrict__ xr, int n) {
  __shared__ float sW[2 * CIN * HC];
  for (int i = threadIdx.x; i < CIN * HC; i += blockDim.x) {
    sW[i] = Wl[i];
    sW[CIN * HC + i] = Wr[i];
  }
  __syncthreads();
  int idx = blockIdx.x * blockDim.x + threadIdx.x;
  if (idx >= n * HC) return;
  int node = idx / HC;
  int j = idx - node * HC;
  float al = bl[j], ar = br[j];
  const float* xrow = x + (size_t)node * CIN;
#pragma unroll
  for (int k = 0; k < CIN; k++) {
    float xv = xrow[k];
    al = fmaf(xv, sW[k * HC + j], al);
    ar = fmaf(xv, sW[CIN * HC + k * HC + j], ar);
  }
  xl[idx] = al;
  xr[idx] = ar;
}

// ---------------- fused edge pass: scores + softmax + aggregate + epilogue ----------------
// One thread per (node, head). CSR gather of xl[src]; den/acc in registers.
// MODE 0: +bias,BN   1: +bias,BN,ELU   2: raw acc/den (layer 4, epilogue elsewhere)

template <int H, int C, int MODE>
__global__ void edge_kernel(const float* __restrict__ xl, const float* __restrict__ xr,
                            const int* __restrict__ indptr, const int* __restrict__ csrc,
                            const float* __restrict__ att, const float* __restrict__ bias,
                            const float* __restrict__ g, const float* __restrict__ be,
                            const float* __restrict__ rm, const float* __restrict__ rv,
                            float* __restrict__ out, int n) {
  constexpr int HC = H * C;
  int t = blockIdx.x * blockDim.x + threadIdx.x;
  if (t >= n * H) return;
  int node = t / H;
  int h = t - node * H;

  float xr_reg[C], att_reg[C];
  const float2* xrp = reinterpret_cast<const float2*>(xr + (size_t)node * HC + h * C);
#pragma unroll
  for (int i = 0; i < C / 2; i++) {
    float2 v = xrp[i];
    xr_reg[2 * i] = v.x;
    xr_reg[2 * i + 1] = v.y;
  }
#pragma unroll
  for (int c = 0; c < C; c++) att_reg[c] = att[h * C + c];

  float acc[C];
#pragma unroll
  for (int c = 0; c < C; c++) acc[c] = 0.f;
  float den = 0.f;

  int p0 = indptr[node], p1 = indptr[node + 1];
  for (int p = p0; p < p1; p++) {
    int s = csrc[p];
    const float2* xsp = reinterpret_cast<const float2*>(xl + (size_t)s * HC + h * C);
    float xs[C];
#pragma unroll
    for (int i = 0; i < C / 2; i++) {
      float2 v = xsp[i];
      xs[2 * i] = v.x;
      xs[2 * i + 1] = v.y;
    }
    float e = 0.f;
#pragma unroll
    for (int c = 0; c < C; c++) {
      float m = xs[c] + xr_reg[c];
      m = (m > 0.f) ? m : 0.2f * m;
      e = fmaf(att_reg[c], m, e);
    }
    float ex = expf(e);
    den += ex;
#pragma unroll
    for (int c = 0; c < C; c++) acc[c] = fmaf(ex, xs[c], acc[c]);
  }

  float inv = 1.f / den;
  float* orow = out + (size_t)node * HC + h * C;
#pragma unroll
  for (int c = 0; c < C; c++) {
    float val = acc[c] * inv;
    if constexpr (MODE == 2) {
      orow[c] = val;
    } else {
      int j = h * C + c;
      val += bias[j];
      float sc = g[j] * rsqrtf(rv[j] + BN_EPS);
      val = fmaf(sc, val - rm[j], be[j]);
      if constexpr (MODE == 1) val = (val > 0.f) ? val : expm1f(val);
      orow[c] = val;
    }
  }
}

// ---------------- layer-4 tail: mean over heads + bias + BN + mu/logvar heads ----------------

__global__ void final_kernel(const float* __restrict__ r4, const float* __restrict__ b4,
                             const float* __restrict__ g4, const float* __restrict__ be4,
                             const float* __restrict__ rm4, const float* __restrict__ rv4,
                             const float* __restrict__ Wmu, const float* __restrict__ bmu,
                             const float* __restrict__ Wlv, const float* __restrict__ blv,
                             float* __restrict__ out, int n) {
  int node = blockIdx.x * blockDim.x + threadIdx.x;
  if (node >= n) return;
  float hsum[10];
#pragma unroll
  for (int c = 0; c < 10; c++) hsum[c] = 0.f;
  const float* r = r4 + (size_t)node * 50;
#pragma unroll
  for (int h = 0; h < 5; h++)
#pragma unroll
    for (int c = 0; c < 10; c++) hsum[c] += r[h * 10 + c];
  float hv[10];
#pragma unroll
  for (int c = 0; c < 10; c++) {
    float v = hsum[c] * 0.2f + b4[c];
    float sc = g4[c] * rsqrtf(rv4[c] + BN_EPS);
    hv[c] = fmaf(sc, v - rm4[c], be4[c]);
  }
#pragma unroll
  for (int j = 0; j < 10; j++) {
    float mu = bmu[j], lv = blv[j];
#pragma unroll
    for (int c = 0; c < 10; c++) {
      mu = fmaf(hv[c], Wmu[c * 10 + j], mu);
      lv = fmaf(hv[c], Wlv[c * 10 + j], lv);
    }
    out[(size_t)node * 10 + j] = mu;
    out[(size_t)n * 10 + (size_t)node * 10 + j] = lv;
  }
}

// ---------------- launch ----------------

extern "C" void kernel_launch(void* const* d_in, const int* in_sizes, int n_in,
                              void* d_out, int out_size, void* d_ws, size_t ws_size,
                              hipStream_t stream) {
  const float* x = (const float*)d_in[0];
  const int* ei = (const int*)d_in[1];
  const int n = in_sizes[0] / 22;
  const int E = in_sizes[1] / 2;
  const int etot = E + n;

  auto P = [&](int i) { return (const float*)d_in[i]; };

  char* ws = (char*)d_ws;
  size_t off = 0;
  auto alloc = [&](size_t bytes) -> void* {
    void* p = ws + off;
    off += (bytes + 255) & ~(size_t)255;
    return p;
  };
  float* xl = (float*)alloc((size_t)n * 54 * 4);
  float* xr = (float*)alloc((size_t)n * 54 * 4);
  float* hb = (float*)alloc((size_t)n * 54 * 4);
  int* deg = (int*)alloc((size_t)n * 4);
  int* cursor = (int*)alloc((size_t)n * 4);
  int* indptr = (int*)alloc((size_t)(n + 1) * 4);
  int* csrc = (int*)alloc((size_t)etot * 4);

  hipMemsetAsync(deg, 0, (size_t)n * 4, stream);
  unsigned eb = (unsigned)((etot + 255) / 256);
  hist_kernel<<<eb, 256, 0, stream>>>(ei, deg, E, n);
  scan_kernel<<<1, 1024, 0, stream>>>(deg, indptr, cursor, n);
  scatter_kernel<<<eb, 256, 0, stream>>>(ei, cursor, csrc, E, n);

  // layer 1: cin=22, H=3, C=18, concat, BN+ELU
  transform_kernel<22, 54><<<(unsigned)(((size_t)n * 54 + 255) / 256), 256, 0, stream>>>(
      x, P(2), P(3), P(4), P(5), xl, xr, n);
  edge_kernel<3, 18, 1><<<(unsigned)(((size_t)n * 3 + 255) / 256), 256, 0, stream>>>(
      xl, xr, indptr, csrc, P(6), P(7), P(8), P(9), P(10), P(11), hb, n);

  // layer 2: cin=54, H=3, C=14, concat, BN
  transform_kernel<54, 42><<<(unsigned)(((size_t)n * 42 + 255) / 256), 256, 0, stream>>>(
      hb, P(12), P(13), P(14), P(15), xl, xr, n);
  edge_kernel<3, 14, 0><<<(unsigned)(((size_t)n * 3 + 255) / 256), 256, 0, stream>>>(
      xl, xr, indptr, csrc, P(16), P(17), P(18), P(19), P(20), P(21), hb, n);

  // layer 3: cin=42, H=3, C=12, concat, BN
  transform_kernel<42, 36><<<(unsigned)(((size_t)n * 36 + 255) / 256), 256, 0, stream>>>(
      hb, P(22), P(23), P(24), P(25), xl, xr, n);
  edge_kernel<3, 12, 0><<<(unsigned)(((size_t)n * 3 + 255) / 256), 256, 0, stream>>>(
      xl, xr, indptr, csrc, P(26), P(27), P(28), P(29), P(30), P(31), hb, n);

  // layer 4: cin=36, H=5, C=10, mean over heads (raw out; epilogue in final_kernel)
  transform_kernel<36, 50><<<(unsigned)(((size_t)n * 50 + 255) / 256), 256, 0, stream>>>(
      hb, P(32), P(33), P(34), P(35), xl, xr, n);
  edge_kernel<5, 10, 2><<<(unsigned)(((size_t)n * 5 + 255) / 256), 256, 0, stream>>>(
      xl, xr, indptr, csrc, P(36), nullptr, nullptr, nullptr, nullptr, nullptr, hb, n);

  final_kernel<<<(unsigned)((n + 255) / 256), 256, 0, stream>>>(
      hb, P(37), P(38), P(39), P(40), P(41), P(42), P(43), P(44), P(45), (float*)d_out, n);
}

// Round 2
// 661.825 us; speedup vs baseline: 1.4836x; 1.4836x over previous
//
#include <hip/hip_runtime.h>

#define BN_EPS 1e-5f

typedef _Float16 half_t;
typedef _Float16 half2_t __attribute__((ext_vector_type(2)));

// ---------------- CSR build ----------------
// pass 1: rank[e] = position of edge e within its dst segment (atomic histogram)
__global__ void hist_kernel(const int* __restrict__ ei, int* __restrict__ deg,
                            int* __restrict__ rank, int E, int n) {
  int e = blockIdx.x * blockDim.x + threadIdx.x;
  if (e >= E + n) return;
  int d = (e < E) ? ei[E + e] : (e - E);
  rank[e] = atomicAdd(&deg[d], 1);
}

// scan stage A: per-block (1024 elems) sums
__global__ void __launch_bounds__(256) block_sum_kernel(const int* __restrict__ deg,
                                                        int* __restrict__ bsum, int n) {
  __shared__ int ws[4];
  int base = blockIdx.x * 1024;
  int s = 0;
  for (int i = threadIdx.x; i < 1024; i += 256) {
    int idx = base + i;
    s += (idx < n) ? deg[idx] : 0;
  }
#pragma unroll
  for (int off = 32; off; off >>= 1) s += __shfl_down(s, off, 64);
  int lane = threadIdx.x & 63, wid = threadIdx.x >> 6;
  if (lane == 0) ws[wid] = s;
  __syncthreads();
  if (threadIdx.x == 0) bsum[blockIdx.x] = ws[0] + ws[1] + ws[2] + ws[3];
}

// scan stage B: single block, exclusive scan of block sums (nb <= 1024)
__global__ void __launch_bounds__(1024) scan_sums_kernel(int* __restrict__ bsum, int nb) {
  __shared__ int wsum[16];
  int tid = threadIdx.x, lane = tid & 63, wid = tid >> 6;
  int v = (tid < nb) ? bsum[tid] : 0;
  int incl = v;
#pragma unroll
  for (int off = 1; off < 64; off <<= 1) {
    int t = __shfl_up(incl, off, 64);
    if (lane >= off) incl += t;
  }
  if (lane == 63) wsum[wid] = incl;
  __syncthreads();
  if (wid == 0 && lane < 16) {
    int s = wsum[lane];
#pragma unroll
    for (int off = 1; off < 16; off <<= 1) {
      int t = __shfl_up(s, off, 16);
      if (lane >= off) s += t;
    }
    wsum[lane] = s;
  }
  __syncthreads();
  int woff = (wid > 0) ? wsum[wid - 1] : 0;
  if (tid < nb) bsum[tid] = incl + woff - v;  // exclusive
}

// scan stage C: per-block exclusive scan + block offset -> indptr
__global__ void __launch_bounds__(1024) scan_block_kernel(const int* __restrict__ deg,
                                                          const int* __restrict__ boff,
                                                          int* __restrict__ indptr, int n) {
  __shared__ int wsum[16];
  int tid = threadIdx.x, lane = tid & 63, wid = tid >> 6;
  int i = blockIdx.x * 1024 + tid;
  int v = (i < n) ? deg[i] : 0;
  int incl = v;
#pragma unroll
  for (int off = 1; off < 64; off <<= 1) {
    int t = __shfl_up(incl, off, 64);
    if (lane >= off) incl += t;
  }
  if (lane == 63) wsum[wid] = incl;
  __syncthreads();
  if (wid == 0 && lane < 16) {
    int s = wsum[lane];
#pragma unroll
    for (int off = 1; off < 16; off <<= 1) {
      int t = __shfl_up(s, off, 16);
      if (lane >= off) s += t;
    }
    wsum[lane] = s;
  }
  __syncthreads();
  int woff = (wid > 0) ? wsum[wid - 1] : 0;
  if (i < n) indptr[i + 1] = incl + woff + boff[blockIdx.x];
  if (i == 0) indptr[0] = 0;
}

// pass 2: place srcs (no atomics; random 4B write is unavoidable)
__global__ void place_kernel(const int* __restrict__ ei, const int* __restrict__ rank,
                             const int* __restrict__ indptr, int* __restrict__ csrc,
                             int E, int n) {
  int e = blockIdx.x * blockDim.x + threadIdx.x;
  if (e >= E + n) return;
  int s, d;
  if (e < E) { s = ei[e]; d = ei[E + e]; } else { s = e - E; d = s; }
  csrc[indptr[d] + rank[e]] = s;
}

// ---------------- node transform: xl(fp16) = x@Wl+bl, xr(fp32) = x@Wr+br ----------------

template <int CIN, int HC>
__global__ void __launch_bounds__(256) transform_kernel(
    const float* __restrict__ x, const float* __restrict__ Wl, const float* __restrict__ Wr,
    const float* __restrict__ bl, const float* __restrict__ br, half_t* __restrict__ xl,
    float* __restrict__ xr, int n) {
  __shared__ float sW[2 * CIN * HC];
  for (int i = threadIdx.x; i < CIN * HC; i += blockDim.x) {
    sW[i] = Wl[i];
    sW[CIN * HC + i] = Wr[i];
  }
  __syncthreads();
  int idx = blockIdx.x * blockDim.x + threadIdx.x;
  if (idx >= n * HC) return;
  int node = idx / HC;
  int j = idx - node * HC;
  float al = bl[j], ar = br[j];
  const float* xrow = x + (size_t)node * CIN;
#pragma unroll
  for (int k = 0; k < CIN; k++) {
    float xv = xrow[k];
    al = fmaf(xv, sW[k * HC + j], al);
    ar = fmaf(xv, sW[CIN * HC + k * HC + j], ar);
  }
  xl[idx] = (half_t)al;
  xr[idx] = ar;
}

// ---------------- fused edge pass ----------------
// One thread per (node, head). CSR gather of fp16 xl[src]; den/acc in registers.
// 2-deep software pipeline on rows, 2-ahead on csrc.
// MODE 0: +bias,BN   1: +bias,BN,ELU   2: raw acc/den (layer 4)

template <int H, int C, int MODE>
__global__ void __launch_bounds__(256) edge_kernel(
    const half_t* __restrict__ xl, const float* __restrict__ xr,
    const int* __restrict__ indptr, const int* __restrict__ csrc,
    const float* __restrict__ att, const float* __restrict__ bias,
    const float* __restrict__ g, const float* __restrict__ be,
    const float* __restrict__ rm, const float* __restrict__ rv,
    float* __restrict__ out, int n) {
  constexpr int HC = H * C;
  constexpr int C2 = C / 2;
  int t = blockIdx.x * blockDim.x + threadIdx.x;
  if (t >= n * H) return;
  int node = t / H;
  int h = t - node * H;

  float xr_reg[C], att_reg[C];
  const float2* xrp = reinterpret_cast<const float2*>(xr + (size_t)node * HC + h * C);
#pragma unroll
  for (int i = 0; i < C2; i++) {
    float2 v = xrp[i];
    xr_reg[2 * i] = v.x;
    xr_reg[2 * i + 1] = v.y;
  }
#pragma unroll
  for (int c = 0; c < C; c++) att_reg[c] = att[h * C + c];

  float acc[C];
#pragma unroll
  for (int c = 0; c < C; c++) acc[c] = 0.f;
  float den = 0.f;

  int p0 = indptr[node], p1 = indptr[node + 1];
  if (p1 > p0) {
    int s_cur = csrc[p0];
    int s_next = (p0 + 1 < p1) ? csrc[p0 + 1] : s_cur;
    half2_t cur[C2];
    {
      const half2_t* xp = reinterpret_cast<const half2_t*>(xl + (size_t)s_cur * HC + h * C);
#pragma unroll
      for (int i = 0; i < C2; i++) cur[i] = xp[i];
    }
    for (int p = p0; p < p1; ++p) {
      int s_nn = (p + 2 < p1) ? csrc[p + 2] : s_next;
      half2_t nxt[C2];
      const half2_t* xp = reinterpret_cast<const half2_t*>(xl + (size_t)s_next * HC + h * C);
#pragma unroll
      for (int i = 0; i < C2; i++) nxt[i] = xp[i];

      float xs[C];
#pragma unroll
      for (int i = 0; i < C2; i++) {
        xs[2 * i] = (float)cur[i].x;
        xs[2 * i + 1] = (float)cur[i].y;
      }
      float e = 0.f;
#pragma unroll
      for (int c = 0; c < C; c++) {
        float m = xs[c] + xr_reg[c];
        m = (m > 0.f) ? m : 0.2f * m;
        e = fmaf(att_reg[c], m, e);
      }
      float ex = __expf(e);
      den += ex;
#pragma unroll
      for (int c = 0; c < C; c++) acc[c] = fmaf(ex, xs[c], acc[c]);

#pragma unroll
      for (int i = 0; i < C2; i++) cur[i] = nxt[i];
      s_next = s_nn;
    }
  }

  float inv = 1.f / den;
  float* orow = out + (size_t)node * HC + h * C;
#pragma unroll
  for (int c = 0; c < C; c++) {
    float val = acc[c] * inv;
    if constexpr (MODE == 2) {
      orow[c] = val;
    } else {
      int j = h * C + c;
      val += bias[j];
      float sc = g[j] * rsqrtf(rv[j] + BN_EPS);
      val = fmaf(sc, val - rm[j], be[j]);
      if constexpr (MODE == 1) val = (val > 0.f) ? val : expm1f(val);
      orow[c] = val;
    }
  }
}

// ---------------- layer-4 tail: mean over heads + bias + BN + mu/logvar heads ----------------

__global__ void final_kernel(const float* __restrict__ r4, const float* __restrict__ b4,
                             const float* __restrict__ g4, const float* __restrict__ be4,
                             const float* __restrict__ rm4, const float* __restrict__ rv4,
                             const float* __restrict__ Wmu, const float* __restrict__ bmu,
                             const float* __restrict__ Wlv, const float* __restrict__ blv,
                             float* __restrict__ out, int n) {
  int node = blockIdx.x * blockDim.x + threadIdx.x;
  if (node >= n) return;
  float hsum[10];
#pragma unroll
  for (int c = 0; c < 10; c++) hsum[c] = 0.f;
  const float* r = r4 + (size_t)node * 50;
#pragma unroll
  for (int h = 0; h < 5; h++)
#pragma unroll
    for (int c = 0; c < 10; c++) hsum[c] += r[h * 10 + c];
  float hv[10];
#pragma unroll
  for (int c = 0; c < 10; c++) {
    float v = hsum[c] * 0.2f + b4[c];
    float sc = g4[c] * rsqrtf(rv4[c] + BN_EPS);
    hv[c] = fmaf(sc, v - rm4[c], be4[c]);
  }
#pragma unroll
  for (int j = 0; j < 10; j++) {
    float mu = bmu[j], lv = blv[j];
#pragma unroll
    for (int c = 0; c < 10; c++) {
      mu = fmaf(hv[c], Wmu[c * 10 + j], mu);
      lv = fmaf(hv[c], Wlv[c * 10 + j], lv);
    }
    out[(size_t)node * 10 + j] = mu;
    out[(size_t)n * 10 + (size_t)node * 10 + j] = lv;
  }
}

// ---------------- launch ----------------

extern "C" void kernel_launch(void* const* d_in, const int* in_sizes, int n_in,
                              void* d_out, int out_size, void* d_ws, size_t ws_size,
                              hipStream_t stream) {
  const float* x = (const float*)d_in[0];
  const int* ei = (const int*)d_in[1];
  const int n = in_sizes[0] / 22;
  const int E = in_sizes[1] / 2;
  const int etot = E + n;

  auto P = [&](int i) { return (const float*)d_in[i]; };

  char* ws = (char*)d_ws;
  size_t off = 0;
  auto alloc = [&](size_t bytes) -> void* {
    void* p = ws + off;
    off += (bytes + 255) & ~(size_t)255;
    return p;
  };
  half_t* xl = (half_t*)alloc((size_t)n * 54 * 2);
  float* xr = (float*)alloc((size_t)n * 54 * 4);
  float* hb = (float*)alloc((size_t)n * 54 * 4);
  int* deg = (int*)alloc((size_t)n * 4);
  int* indptr = (int*)alloc((size_t)(n + 1) * 4);
  int* rank = (int*)alloc((size_t)etot * 4);
  int* csrc = (int*)alloc((size_t)etot * 4);
  int nb = (n + 1023) / 1024;
  int* bsum = (int*)alloc((size_t)nb * 4);

  hipMemsetAsync(deg, 0, (size_t)n * 4, stream);
  unsigned eb = (unsigned)((etot + 255) / 256);
  hist_kernel<<<eb, 256, 0, stream>>>(ei, deg, rank, E, n);
  block_sum_kernel<<<(unsigned)nb, 256, 0, stream>>>(deg, bsum, n);
  scan_sums_kernel<<<1, 1024, 0, stream>>>(bsum, nb);
  scan_block_kernel<<<(unsigned)nb, 1024, 0, stream>>>(deg, bsum, indptr, n);
  place_kernel<<<eb, 256, 0, stream>>>(ei, rank, indptr, csrc, E, n);

  // layer 1: cin=22, H=3, C=18, concat, BN+ELU
  transform_kernel<22, 54><<<(unsigned)(((size_t)n * 54 + 255) / 256), 256, 0, stream>>>(
      x, P(2), P(3), P(4), P(5), xl, xr, n);
  edge_kernel<3, 18, 1><<<(unsigned)(((size_t)n * 3 + 255) / 256), 256, 0, stream>>>(
      xl, xr, indptr, csrc, P(6), P(7), P(8), P(9), P(10), P(11), hb, n);

  // layer 2: cin=54, H=3, C=14, concat, BN
  transform_kernel<54, 42><<<(unsigned)(((size_t)n * 42 + 255) / 256), 256, 0, stream>>>(
      hb, P(12), P(13), P(14), P(15), xl, xr, n);
  edge_kernel<3, 14, 0><<<(unsigned)(((size_t)n * 3 + 255) / 256), 256, 0, stream>>>(
      xl, xr, indptr, csrc, P(16), P(17), P(18), P(19), P(20), P(21), hb, n);

  // layer 3: cin=42, H=3, C=12, concat, BN
  transform_kernel<42, 36><<<(unsigned)(((size_t)n * 36 + 255) / 256), 256, 0, stream>>>(
      hb, P(22), P(23), P(24), P(25), xl, xr, n);
  edge_kernel<3, 12, 0><<<(unsigned)(((size_t)n * 3 + 255) / 256), 256, 0, stream>>>(
      xl, xr, indptr, csrc, P(26), P(27), P(28), P(29), P(30), P(31), hb, n);

  // layer 4: cin=36, H=5, C=10, mean over heads (raw out; epilogue in final_kernel)
  transform_kernel<36, 50><<<(unsigned)(((size_t)n * 50 + 255) / 256), 256, 0, stream>>>(
      hb, P(32), P(33), P(34), P(35), xl, xr, n);
  edge_kernel<5, 10, 2><<<(unsigned)(((size_t)n * 5 + 255) / 256), 256, 0, stream>>>(
      xl, xr, indptr, csrc, P(36), nullptr, nullptr, nullptr, nullptr, nullptr, hb, n);

  final_kernel<<<(unsigned)((n + 255) / 256), 256, 0, stream>>>(
      hb, P(37), P(38), P(39), P(40), P(41), P(42), P(43), P(44), P(45), (float*)d_out, n);
}